// Round 4
// baseline (107.126 us; speedup 1.0000x reference)
//
#include <hip/hip_runtime.h>

typedef float f4 __attribute__((ext_vector_type(4)));
typedef float f2 __attribute__((ext_vector_type(2)));

#define PAD 68      // LDS row pitch (floats); 68%32=4 spreads banks
#define NBLK 256

// ws float layout:
// [0, 3145728)        pT[3][4096][256]  transposed partials (12.6 MB)
// [3145728, +256)     bpart[256]        per-block v partials
// [3145984, +2)       cnt, cnt2 (uints) reset by hipMemsetAsync each call

__global__ __launch_bounds__(1024) void fused_all_kernel(
    const float* __restrict__ p1, const float* __restrict__ p2,
    float* __restrict__ pT, float* __restrict__ bpart,
    unsigned* __restrict__ cnt, float* __restrict__ out)
{
    __shared__ float la[32 * PAD];
    __shared__ float lb[32 * PAD];
    __shared__ float nred[64][17];
    __shared__ float sa[32], sb[32];
    __shared__ float vred[16];
    __shared__ float fr[256];
    __shared__ unsigned lastf;
    const int t   = threadIdx.x;
    const int blk = blockIdx.x;
    const int b   = blk >> 5;     // batch 0..7
    const int oi  = blk & 31;     // pooled row strip 0..31

    // ---- phase 1a: pool 4x4 means into LDS [oj][c]
    #pragma unroll
    for (int k = 0; k < 2; ++k) {
        const int idx = k * 1024 + t;     // 0..2047
        const int c   = idx >> 5;
        const int oj  = idx & 31;
        const long off = (long)((b * 64 + c) * 128 + oi * 4) * 128 + oj * 4;
        const float* s1 = p1 + off;
        const float* s2 = p2 + off;
        f4 va = *(const f4*)(s1) + *(const f4*)(s1 + 128)
              + *(const f4*)(s1 + 256) + *(const f4*)(s1 + 384);
        f4 vb = *(const f4*)(s2) + *(const f4*)(s2 + 128)
              + *(const f4*)(s2 + 256) + *(const f4*)(s2 + 384);
        la[oj * PAD + c] = ((va[0] + va[1]) + (va[2] + va[3])) * 0.0625f;
        lb[oj * PAD + c] = ((vb[0] + vb[1]) + (vb[2] + vb[3])) * 0.0625f;
    }
    __syncthreads();

    // ---- phase 1b: row L2 norms over 64 channels
    {
        const int r = t & 31, g = t >> 5;        // g = 0..31
        const int m = g >> 4, q = g & 15;        // input, 4-ch chunk
        const float* src = m ? lb : la;
        float ss = 0.f;
        #pragma unroll
        for (int j = 0; j < 4; ++j) {
            const float v = src[r * PAD + q * 4 + j];
            ss = fmaf(v, v, ss);
        }
        nred[m * 32 + r][q] = ss;
    }
    __syncthreads();
    if (t < 64) {
        const int m = t >> 5, r = t & 31;
        float ss = 0.f;
        #pragma unroll
        for (int q = 0; q < 16; ++q) ss += nred[m * 32 + r][q];
        const float rs = 1.0f / fmaxf(sqrtf(ss), 1e-8f);
        if (m) sb[r] = rs; else sa[r] = rs;
    }
    __syncthreads();

    #pragma unroll
    for (int k = 0; k < 2; ++k) {
        const int idx = k * 1024 + t;
        const int c = idx >> 5, oj = idx & 31;
        la[oj * PAD + c] *= sa[oj];
        lb[oj * PAD + c] *= sb[oj];
    }
    __syncthreads();

    // ---- phase 1c: three 64x64 Grams, 2x2 tile per thread
    const int c1 = (t >> 5) * 2;
    const int c2 = (t & 31) * 2;
    f2 aa0 = {}, aa1 = {}, ab0 = {}, ab1 = {}, bb0 = {}, bb1 = {};

    #pragma unroll 8
    for (int r = 0; r < 32; ++r) {
        const f2 a1 = *(const f2*)&la[r * PAD + c1];
        const f2 a2 = *(const f2*)&la[r * PAD + c2];
        const f2 b1 = *(const f2*)&lb[r * PAD + c1];
        const f2 b2 = *(const f2*)&lb[r * PAD + c2];
        aa0 += a2 * a1[0];  aa1 += a2 * a1[1];
        ab0 += b2 * a1[0];  ab1 += b2 * a1[1];
        bb0 += b2 * b1[0];  bb1 += b2 * b1[1];
    }

    // ---- store transposed: pT[g][e][blk], e = row*64 + col
    {
        const int e0 = c1 * 64 + c2;          // (c1,   c2)
        const int e1 = e0 + 64;               // (c1+1, c2)
        pT[(0 * 4096 + e0    ) * 256 + blk] = aa0[0];
        pT[(0 * 4096 + e0 + 1) * 256 + blk] = aa0[1];
        pT[(0 * 4096 + e1    ) * 256 + blk] = aa1[0];
        pT[(0 * 4096 + e1 + 1) * 256 + blk] = aa1[1];
        pT[(1 * 4096 + e0    ) * 256 + blk] = ab0[0];
        pT[(1 * 4096 + e0 + 1) * 256 + blk] = ab0[1];
        pT[(1 * 4096 + e1    ) * 256 + blk] = ab1[0];
        pT[(1 * 4096 + e1 + 1) * 256 + blk] = ab1[1];
        pT[(2 * 4096 + e0    ) * 256 + blk] = bb0[0];
        pT[(2 * 4096 + e0 + 1) * 256 + blk] = bb0[1];
        pT[(2 * 4096 + e1    ) * 256 + blk] = bb1[0];
        pT[(2 * 4096 + e1 + 1) * 256 + blk] = bb1[1];
    }

    // ---- grid soft barrier (all 256 blocks co-resident: 1 block/CU)
    __syncthreads();   // drains this block's stores (vmcnt(0) before s_barrier)
    if (t == 0) {
        __hip_atomic_fetch_add(cnt, 1u, __ATOMIC_ACQ_REL,
                               __HIP_MEMORY_SCOPE_AGENT);
        while (__hip_atomic_load(cnt, __ATOMIC_ACQUIRE,
                                 __HIP_MEMORY_SCOPE_AGENT) < NBLK) {}
    }
    __syncthreads();

    // ---- phase 2: each wave reduces one gram entry (1 KB coalesced / gram)
    {
        const int w = t >> 6;            // wave 0..15
        const int l = t & 63;
        const int e = blk * 16 + w;      // entry 0..4095
        float s3[3];
        #pragma unroll
        for (int g = 0; g < 3; ++g) {
            const f4 v = *(const f4*)&pT[((g * 4096 + e) * 256) + l * 4];
            float s = (v[0] + v[1]) + (v[2] + v[3]);
            s += __shfl_xor(s, 1);
            s += __shfl_xor(s, 2);
            s += __shfl_xor(s, 4);
            s += __shfl_xor(s, 8);
            s += __shfl_xor(s, 16);
            s += __shfl_xor(s, 32);
            s3[g] = s;
        }
        if (l == 0)
            vred[w] = fmaf(s3[0], s3[0],
                      fmaf(s3[2], s3[2], -2.0f * (s3[1] * s3[1])));
    }
    __syncthreads();

    // ---- ticket: last block sums the 256 block partials
    if (t == 0) {
        float s = 0.f;
        #pragma unroll
        for (int i = 0; i < 16; ++i) s += vred[i];
        __hip_atomic_store(&bpart[blk], s, __ATOMIC_RELEASE,
                           __HIP_MEMORY_SCOPE_AGENT);
        unsigned old = __hip_atomic_fetch_add(cnt + 1, 1u, __ATOMIC_ACQ_REL,
                                              __HIP_MEMORY_SCOPE_AGENT);
        lastf = (old == NBLK - 1) ? 1u : 0u;
    }
    __syncthreads();

    if (lastf) {   // block-uniform
        if (t < 256)
            fr[t] = __hip_atomic_load(&bpart[t], __ATOMIC_ACQUIRE,
                                      __HIP_MEMORY_SCOPE_AGENT);
        __syncthreads();
        for (int s2 = 128; s2 > 0; s2 >>= 1) {
            if (t < s2) fr[t] += fr[t + s2];
            __syncthreads();
        }
        if (t == 0) out[0] = fr[0] * (1.0f / 67108864.0f);  // / 8192^2
    }
}

extern "C" void kernel_launch(void* const* d_in, const int* in_sizes, int n_in,
                              void* d_out, int out_size, void* d_ws, size_t ws_size,
                              hipStream_t stream)
{
    const float* p1 = (const float*)d_in[0];
    const float* p2 = (const float*)d_in[1];
    float* ws    = (float*)d_ws;
    float* pT    = ws;                          // 3*4096*256
    float* bpart = ws + 3 * 4096 * 256;         // 256
    unsigned* cnt = (unsigned*)(bpart + 256);   // cnt, cnt2

    hipMemsetAsync(cnt, 0, 2 * sizeof(unsigned), stream);
    fused_all_kernel<<<NBLK, 1024, 0, stream>>>(p1, p2, pT, bpart, cnt,
                                                (float*)d_out);
}

// Round 5
// 39.827 us; speedup vs baseline: 2.6898x; 2.6898x over previous
//
#include <hip/hip_runtime.h>

typedef float f4 __attribute__((ext_vector_type(4)));
typedef float f2 __attribute__((ext_vector_type(2)));

#define PAD 68              // LDS row pitch (floats); 68%32=4 spreads banks
#define NPART 256           // gram blocks = partial count
#define PART_STRIDE 12288   // 3 * 64*64 floats per block partial
#define NBLK2 64            // reduce-kernel blocks

// ws layout (floats):
// [0, 3145728)      partials [256][3][4096]
// [3145728, +64)    per-block v partials (K2)
// [3145792]         uint counter (K2 ticket; reset by K1 block 0)

__global__ __launch_bounds__(1024) void fused_gram_kernel(
    const float* __restrict__ p1, const float* __restrict__ p2,
    float* __restrict__ partials, unsigned* __restrict__ cnt)
{
    __shared__ float la[32 * PAD];
    __shared__ float lb[32 * PAD];
    __shared__ float nred[64][17];
    __shared__ float sa[32], sb[32];
    const int t  = threadIdx.x;
    const int b  = blockIdx.x >> 5;   // batch 0..7
    const int oi = blockIdx.x & 31;   // pooled row strip 0..31

    if (blockIdx.x == 0 && t == 0) *cnt = 0u;   // reset K2's ticket each call

    // ---- pool 4x4 means: 64 ch x 32 oj per input, into LDS [oj][c]
    #pragma unroll
    for (int k = 0; k < 2; ++k) {
        const int idx = k * 1024 + t;     // 0..2047
        const int c   = idx >> 5;
        const int oj  = idx & 31;
        const long off = (long)((b * 64 + c) * 128 + oi * 4) * 128 + oj * 4;
        const float* s1 = p1 + off;
        const float* s2 = p2 + off;
        f4 va = *(const f4*)(s1) + *(const f4*)(s1 + 128)
              + *(const f4*)(s1 + 256) + *(const f4*)(s1 + 384);
        f4 vb = *(const f4*)(s2) + *(const f4*)(s2 + 128)
              + *(const f4*)(s2 + 256) + *(const f4*)(s2 + 384);
        la[oj * PAD + c] = ((va[0] + va[1]) + (va[2] + va[3])) * 0.0625f;
        lb[oj * PAD + c] = ((vb[0] + vb[1]) + (vb[2] + vb[3])) * 0.0625f;
    }
    __syncthreads();

    // ---- row L2 norms over 64 ch: 32 rows x 2 inputs x 16 chunks of 4 ch
    {
        const int r = t & 31, g = t >> 5;        // g = 0..31
        const int m = g >> 4, q = g & 15;        // input, chunk
        const float* src = m ? lb : la;
        float ss = 0.f;
        #pragma unroll
        for (int j = 0; j < 4; ++j) {
            const float v = src[r * PAD + q * 4 + j];
            ss = fmaf(v, v, ss);
        }
        nred[m * 32 + r][q] = ss;
    }
    __syncthreads();
    if (t < 64) {
        const int m = t >> 5, r = t & 31;
        float ss = 0.f;
        #pragma unroll
        for (int q = 0; q < 16; ++q) ss += nred[m * 32 + r][q];
        const float rs = 1.0f / fmaxf(sqrtf(ss), 1e-8f);
        if (m) sb[r] = rs; else sa[r] = rs;
    }
    __syncthreads();

    // ---- scale rows in place
    #pragma unroll
    for (int k = 0; k < 2; ++k) {
        const int idx = k * 1024 + t;
        const int c = idx >> 5, oj = idx & 31;
        la[oj * PAD + c] *= sa[oj];
        lb[oj * PAD + c] *= sb[oj];
    }
    __syncthreads();

    // ---- three 64x64 channel Grams over this block's 32 rows.
    const int c1 = (t >> 5) * 2;      // broadcast within half-wave
    const int c2 = (t & 31) * 2;      // stride-2 across lanes (2-way = free)
    f2 aa0 = {}, aa1 = {}, ab0 = {}, ab1 = {}, bb0 = {}, bb1 = {};

    #pragma unroll 8
    for (int r = 0; r < 32; ++r) {
        const f2 a1 = *(const f2*)&la[r * PAD + c1];
        const f2 a2 = *(const f2*)&la[r * PAD + c2];
        const f2 b1 = *(const f2*)&lb[r * PAD + c1];
        const f2 b2 = *(const f2*)&lb[r * PAD + c2];
        aa0 += a2 * a1[0];  aa1 += a2 * a1[1];
        ab0 += b2 * a1[0];  ab1 += b2 * a1[1];
        bb0 += b2 * b1[0];  bb1 += b2 * b1[1];
    }

    float* P = partials + (long)blockIdx.x * PART_STRIDE;
    *(f2*)&P[0 * 4096 + (c1    ) * 64 + c2] = aa0;
    *(f2*)&P[0 * 4096 + (c1 + 1) * 64 + c2] = aa1;
    *(f2*)&P[1 * 4096 + (c1    ) * 64 + c2] = ab0;
    *(f2*)&P[1 * 4096 + (c1 + 1) * 64 + c2] = ab1;
    *(f2*)&P[2 * 4096 + (c1    ) * 64 + c2] = bb0;
    *(f2*)&P[2 * 4096 + (c1 + 1) * 64 + c2] = bb1;
}

// 64 blocks x 1024 threads. Block owns 64 Gram entries (all 3 grams).
// Wave w (=pc) sums 16 partial-blocks for its 64 entries: every load is one
// contiguous 256 B segment per wave. LDS tree + shfl; ticket finish.
__global__ __launch_bounds__(1024) void reduce_kernel(
    const float* __restrict__ partials, float* __restrict__ bpart,
    unsigned* __restrict__ cnt, float* __restrict__ out)
{
    __shared__ float red[3][16][64];   // [gram][p-chunk][entry-offset]
    __shared__ unsigned lastf;
    const int t  = threadIdx.x;
    const int l  = t & 63;            // entry offset (lane)
    const int pc = t >> 6;            // wave index = p-chunk 0..15
    const int e  = blockIdx.x * 64 + l;

    float s0 = 0.f, s1 = 0.f, s2 = 0.f;
    #pragma unroll
    for (int i = 0; i < 16; ++i) {
        const long pbase = (long)(pc * 16 + i) * PART_STRIDE;
        s0 += partials[pbase + e];
        s1 += partials[pbase + 4096 + e];
        s2 += partials[pbase + 8192 + e];
    }
    red[0][pc][l] = s0;
    red[1][pc][l] = s1;
    red[2][pc][l] = s2;
    __syncthreads();

    if (t < 64) {
        float saa = 0.f, sab = 0.f, sbb = 0.f;
        #pragma unroll
        for (int p = 0; p < 16; ++p) {
            saa += red[0][p][t];
            sab += red[1][p][t];
            sbb += red[2][p][t];
        }
        float v = fmaf(saa, saa, fmaf(sbb, sbb, -2.0f * (sab * sab)));
        // t 0..63 is exactly wave 0: shfl tree, fixed order -> deterministic
        v += __shfl_xor(v, 1);
        v += __shfl_xor(v, 2);
        v += __shfl_xor(v, 4);
        v += __shfl_xor(v, 8);
        v += __shfl_xor(v, 16);
        v += __shfl_xor(v, 32);
        if (t == 0) {
            __hip_atomic_store(&bpart[blockIdx.x], v, __ATOMIC_RELEASE,
                               __HIP_MEMORY_SCOPE_AGENT);
            unsigned old = __hip_atomic_fetch_add(cnt, 1u, __ATOMIC_ACQ_REL,
                                                  __HIP_MEMORY_SCOPE_AGENT);
            lastf = (old == NBLK2 - 1) ? 1u : 0u;
        }
    }
    __syncthreads();

    if (lastf) {       // block-uniform; only the last-arriving block enters
        if (t < 64) {
            float v = __hip_atomic_load(&bpart[t], __ATOMIC_ACQUIRE,
                                        __HIP_MEMORY_SCOPE_AGENT);
            v += __shfl_xor(v, 1);
            v += __shfl_xor(v, 2);
            v += __shfl_xor(v, 4);
            v += __shfl_xor(v, 8);
            v += __shfl_xor(v, 16);
            v += __shfl_xor(v, 32);
            if (t == 0) out[0] = v * (1.0f / 67108864.0f);  // / 8192^2
        }
    }
}

extern "C" void kernel_launch(void* const* d_in, const int* in_sizes, int n_in,
                              void* d_out, int out_size, void* d_ws, size_t ws_size,
                              hipStream_t stream)
{
    const float* p1 = (const float*)d_in[0];
    const float* p2 = (const float*)d_in[1];
    float* ws       = (float*)d_ws;
    float* partials = ws;                                  // 256*12288
    float* bpart    = ws + (long)NPART * PART_STRIDE;      // 64
    unsigned* cnt   = (unsigned*)(bpart + NBLK2);          // 1

    fused_gram_kernel<<<NPART, 1024, 0, stream>>>(p1, p2, partials, cnt);
    reduce_kernel   <<<NBLK2, 1024, 0, stream>>>(partials, bpart, cnt, (float*)d_out);
}